// Round 1
// baseline (2373.577 us; speedup 1.0000x reference)
//
#include <hip/hip_runtime.h>
#include <math.h>

#define NL 16
#define NB 4
#define ND 1024
#define NH 16
#define HD 64
#define NKVH 8
#define NDFF 4096
#define NS 2048
#define SP1 2049
#define NCHUNK 16
#define CH 129          // ceil(2049/16)
#define MUP 0.35f       // 1.4/sqrt(16)
#define SCALE 0.125f    // 1/sqrt(64)
#define EPS 1e-5f

// workspace float offsets
#define WS_H     0
#define WS_X     4096
#define WS_QKV   8192      // [B][2048]: q 0..1023, k 1024..1535, v 1536..2047
#define WS_YO    16384     // [B][1024]
#define WS_GATE  20480     // [B][4096]
#define WS_UP    36864     // [B][4096]
#define WS_YMLP  53248     // [B][1024]
#define WS_OPART 57344     // [B][KVH][NCHUNK][132]
#define WS_OH    (57344 + NB*NKVH*NCHUNK*132)   // [B][1024]

// d_out float offsets
#define OUT_H   0
#define OUT_NK  4096
#define OUT_NV  (4096 + NL*NB*NKVH*SP1*HD)
#define OUT_SC  (4096 + 2*NL*NB*NKVH*SP1*HD)

__device__ __forceinline__ float wsum(float v) {
    v += __shfl_xor(v, 32); v += __shfl_xor(v, 16); v += __shfl_xor(v, 8);
    v += __shfl_xor(v, 4);  v += __shfl_xor(v, 2);  v += __shfl_xor(v, 1);
    return v;
}

__global__ __launch_bounds__(256) void k_init(const float* __restrict__ emb,
                                              const int* __restrict__ cl,
                                              float* __restrict__ ws,
                                              float* __restrict__ out) {
    int j = blockIdx.x * 1024 + threadIdx.x;
    #pragma unroll
    for (int k = 0; k < 4; ++k) {
        int i = j + k * 256;
        if (i < 4096) ws[WS_H + i] = emb[i];
        else          ws[WS_YMLP + i - 4096] = 0.f;
    }
    if (blockIdx.x == 0 && threadIdx.x == 0)
        out[OUT_SC] = (float)(cl[0] + 1);
}

// blocks 0..3: h += mup*y_mlp; zero y_mlp; x = rmsnorm(h)*ln1
// blocks 4..47: zero qkv/y_o/gate/up (45056 floats from WS_QKV)
__global__ __launch_bounds__(256) void k_rms1(const float* __restrict__ ln1,
                                              float* __restrict__ ws, int l) {
    if (blockIdx.x >= 4) {
        int base = WS_QKV + (blockIdx.x - 4) * 1024 + threadIdx.x;
        #pragma unroll
        for (int k = 0; k < 4; ++k) ws[base + k * 256] = 0.f;
        return;
    }
    int b = blockIdx.x, tid = threadIdx.x;
    int wave = tid >> 6, lane = tid & 63;
    __shared__ float sred[4];
    float hv[4]; float ss = 0.f;
    #pragma unroll
    for (int k = 0; k < 4; ++k) {
        int d = tid + k * 256;
        float nh = ws[WS_H + b * 1024 + d] + MUP * ws[WS_YMLP + b * 1024 + d];
        hv[k] = nh;
        ws[WS_H + b * 1024 + d] = nh;
        ws[WS_YMLP + b * 1024 + d] = 0.f;
        ss += nh * nh;
    }
    ss = wsum(ss);
    if (lane == 0) sred[wave] = ss;
    __syncthreads();
    float tot = sred[0] + sred[1] + sred[2] + sred[3];
    float rstd = rsqrtf(tot / (float)ND + EPS);
    #pragma unroll
    for (int k = 0; k < 4; ++k) {
        int d = tid + k * 256;
        ws[WS_X + b * 1024 + d] = hv[k] * rstd * ln1[l * 1024 + d];
    }
}

// x[4,1024] @ {Wq|Wk|Wv} -> qkv accum. grid (8 tiles, 8 ksplit), block 256
__global__ __launch_bounds__(256) void k_qkv(const float* __restrict__ wq,
                                             const float* __restrict__ wk,
                                             const float* __restrict__ wv,
                                             float* __restrict__ ws, int l) {
    __shared__ float xs[512];
    int tid = threadIdx.x;
    int d0 = blockIdx.y * 128;
    #pragma unroll
    for (int k = 0; k < 2; ++k) {
        int idx = tid + k * 256;
        xs[idx] = ws[WS_X + (idx >> 7) * 1024 + d0 + (idx & 127)];
    }
    __syncthreads();
    int col = blockIdx.x * 256 + tid;
    const float* wp; int nc; int c;
    if (col < 1024)       { wp = wq + (size_t)l * ND * 1024; nc = 1024; c = col; }
    else if (col < 1536)  { wp = wk + (size_t)l * ND * 512;  nc = 512;  c = col - 1024; }
    else                  { wp = wv + (size_t)l * ND * 512;  nc = 512;  c = col - 1536; }
    wp += (size_t)d0 * nc + c;
    float a0 = 0.f, a1 = 0.f, a2 = 0.f, a3 = 0.f;
    #pragma unroll 4
    for (int dd = 0; dd < 128; ++dd) {
        float w = wp[(size_t)dd * nc];
        a0 += xs[dd] * w; a1 += xs[128 + dd] * w;
        a2 += xs[256 + dd] * w; a3 += xs[384 + dd] * w;
    }
    atomicAdd(&ws[WS_QKV + 0 * 2048 + col], a0);
    atomicAdd(&ws[WS_QKV + 1 * 2048 + col], a1);
    atomicAdd(&ws[WS_QKV + 2 * 2048 + col], a2);
    atomicAdd(&ws[WS_QKV + 3 * 2048 + col], a3);
}

// flash-decode partial + fused cache copy. grid B*KVH*NCHUNK, block 256 (4 waves)
__global__ __launch_bounds__(256) void k_attn(const float* __restrict__ kc,
                                              const float* __restrict__ vc,
                                              const int* __restrict__ cl,
                                              float* __restrict__ ws,
                                              float* __restrict__ nk,
                                              float* __restrict__ nv, int l) {
    int bid = blockIdx.x;
    int b   = bid / (NKVH * NCHUNK);
    int rem = bid % (NKVH * NCHUNK);
    int kvh = rem / NCHUNK;
    int c   = rem % NCHUNK;
    int s0 = c * CH;
    int s1 = min(s0 + CH, SP1);
    int tid = threadIdx.x, wave = tid >> 6, lane = tid & 63;

    float pos = (float)cl[0];
    int fi = lane & 31;
    float invf = __expf(-(float)fi * (0.28782313662425572f)); // ln(1e4)/32
    float fr = pos * invf;
    float cs = cosf(fr), sn = sinf(fr);

    float q0r = ws[WS_QKV + b * 2048 + (kvh * 2 + 0) * 64 + lane];
    float q1r = ws[WS_QKV + b * 2048 + (kvh * 2 + 1) * 64 + lane];
    float q0p = __shfl_xor(q0r, 32), q1p = __shfl_xor(q1r, 32);
    float sgn = (lane < 32) ? -1.f : 1.f;
    float q0 = q0r * cs + sgn * q0p * sn;
    float q1 = q1r * cs + sgn * q1p * sn;

    __shared__ float sc[2][CH];
    __shared__ float wm[2][4];
    __shared__ float oacc[4][2][64];
    __shared__ float wl[4][2];

    size_t cbase = (size_t)((l * NB + b) * NKVH + kvh);
    float m0 = -1e30f, m1 = -1e30f;
    for (int s = s0 + wave; s < s1; s += 4) {
        float kv;
        if (s < NS) {
            kv = kc[(cbase * NS + s) * 64 + lane];
            nk[(cbase * SP1 + s) * 64 + lane] = kv;
        } else {
            float kr = ws[WS_QKV + b * 2048 + 1024 + kvh * 64 + lane];
            float kp = __shfl_xor(kr, 32);
            kv = kr * cs + sgn * kp * sn;
            nk[(cbase * SP1 + s) * 64 + lane] = kv;
        }
        float d0 = wsum(kv * q0) * SCALE;
        float d1 = wsum(kv * q1) * SCALE;
        if (lane == 0) { sc[0][s - s0] = d0; sc[1][s - s0] = d1; }
        m0 = fmaxf(m0, d0); m1 = fmaxf(m1, d1);
    }
    if (lane == 0) { wm[0][wave] = m0; wm[1][wave] = m1; }
    __syncthreads();
    float M0 = fmaxf(fmaxf(wm[0][0], wm[0][1]), fmaxf(wm[0][2], wm[0][3]));
    float M1 = fmaxf(fmaxf(wm[1][0], wm[1][1]), fmaxf(wm[1][2], wm[1][3]));

    float o0 = 0.f, o1 = 0.f, l0 = 0.f, l1 = 0.f;
    for (int s = s0 + wave; s < s1; s += 4) {
        float vv;
        if (s < NS) {
            vv = vc[(cbase * NS + s) * 64 + lane];
        } else {
            vv = ws[WS_QKV + b * 2048 + 1536 + kvh * 64 + lane];
        }
        nv[(cbase * SP1 + s) * 64 + lane] = vv;
        float p0 = __expf(sc[0][s - s0] - M0);
        float p1 = __expf(sc[1][s - s0] - M1);
        o0 += p0 * vv; o1 += p1 * vv; l0 += p0; l1 += p1;
    }
    oacc[wave][0][lane] = o0;
    oacc[wave][1][lane] = o1;
    if (lane == 0) { wl[wave][0] = l0; wl[wave][1] = l1; }
    __syncthreads();

    int pbase = WS_OPART + ((b * NKVH + kvh) * NCHUNK + c) * 132;
    if (tid < 64) {
        ws[pbase + tid] = oacc[0][0][tid] + oacc[1][0][tid] + oacc[2][0][tid] + oacc[3][0][tid];
    } else if (tid < 128) {
        int d = tid - 64;
        ws[pbase + 64 + d] = oacc[0][1][d] + oacc[1][1][d] + oacc[2][1][d] + oacc[3][1][d];
    } else if (tid == 128) {
        ws[pbase + 128] = M0;
        ws[pbase + 129] = wl[0][0] + wl[1][0] + wl[2][0] + wl[3][0];
        ws[pbase + 130] = M1;
        ws[pbase + 131] = wl[0][1] + wl[1][1] + wl[2][1] + wl[3][1];
    }
}

// combine chunk partials -> o_heads. grid B*KVH, block 64
__global__ __launch_bounds__(64) void k_reduce(float* __restrict__ ws) {
    int b = blockIdx.x >> 3, kvh = blockIdx.x & 7;
    int d = threadIdx.x;
    #pragma unroll
    for (int g = 0; g < 2; ++g) {
        int base = WS_OPART + ((b * NKVH + kvh) * NCHUNK) * 132;
        float m = -1e30f;
        for (int c = 0; c < NCHUNK; ++c)
            m = fmaxf(m, ws[base + c * 132 + 128 + 2 * g]);
        float lt = 0.f, ot = 0.f;
        for (int c = 0; c < NCHUNK; ++c) {
            float f = __expf(ws[base + c * 132 + 128 + 2 * g] - m);
            lt += ws[base + c * 132 + 129 + 2 * g] * f;
            ot += ws[base + c * 132 + g * 64 + d] * f;
        }
        ws[WS_OH + b * 1024 + (kvh * 2 + g) * 64 + d] = ot / lt;
    }
}

// o_heads[4,1024] @ Wo -> y_o. grid (4 tiles, 8 ksplit)
__global__ __launch_bounds__(256) void k_oproj(const float* __restrict__ wo,
                                               float* __restrict__ ws, int l) {
    __shared__ float xs[512];
    int tid = threadIdx.x;
    int d0 = blockIdx.y * 128;
    #pragma unroll
    for (int k = 0; k < 2; ++k) {
        int idx = tid + k * 256;
        xs[idx] = ws[WS_OH + (idx >> 7) * 1024 + d0 + (idx & 127)];
    }
    __syncthreads();
    int col = blockIdx.x * 256 + tid;
    const float* wp = wo + (size_t)l * 1024 * ND + (size_t)d0 * ND + col;
    float a0 = 0.f, a1 = 0.f, a2 = 0.f, a3 = 0.f;
    #pragma unroll 4
    for (int dd = 0; dd < 128; ++dd) {
        float w = wp[(size_t)dd * ND];
        a0 += xs[dd] * w; a1 += xs[128 + dd] * w;
        a2 += xs[256 + dd] * w; a3 += xs[384 + dd] * w;
    }
    atomicAdd(&ws[WS_YO + 0 * 1024 + col], a0);
    atomicAdd(&ws[WS_YO + 1 * 1024 + col], a1);
    atomicAdd(&ws[WS_YO + 2 * 1024 + col], a2);
    atomicAdd(&ws[WS_YO + 3 * 1024 + col], a3);
}

__global__ __launch_bounds__(256) void k_rms2(const float* __restrict__ ln2,
                                              float* __restrict__ ws, int l) {
    int b = blockIdx.x, tid = threadIdx.x;
    int wave = tid >> 6, lane = tid & 63;
    __shared__ float sred[4];
    float hv[4]; float ss = 0.f;
    #pragma unroll
    for (int k = 0; k < 4; ++k) {
        int d = tid + k * 256;
        float nh = ws[WS_H + b * 1024 + d] + MUP * ws[WS_YO + b * 1024 + d];
        hv[k] = nh;
        ws[WS_H + b * 1024 + d] = nh;
        ss += nh * nh;
    }
    ss = wsum(ss);
    if (lane == 0) sred[wave] = ss;
    __syncthreads();
    float tot = sred[0] + sred[1] + sred[2] + sred[3];
    float rstd = rsqrtf(tot / (float)ND + EPS);
    #pragma unroll
    for (int k = 0; k < 4; ++k) {
        int d = tid + k * 256;
        ws[WS_X + b * 1024 + d] = hv[k] * rstd * ln2[l * 1024 + d];
    }
}

// x @ {Wg|Wu} -> gate/up. grid (16 tiles, 8 ksplit, 2 mats)
__global__ __launch_bounds__(256) void k_gateup(const float* __restrict__ wg,
                                                const float* __restrict__ wu,
                                                float* __restrict__ ws, int l) {
    __shared__ float xs[512];
    int tid = threadIdx.x;
    int d0 = blockIdx.y * 128;
    #pragma unroll
    for (int k = 0; k < 2; ++k) {
        int idx = tid + k * 256;
        xs[idx] = ws[WS_X + (idx >> 7) * 1024 + d0 + (idx & 127)];
    }
    __syncthreads();
    int col = blockIdx.x * 256 + tid;
    const float* wsrc = blockIdx.z ? wu : wg;
    int dst = blockIdx.z ? WS_UP : WS_GATE;
    const float* wp = wsrc + (size_t)l * ND * NDFF + (size_t)d0 * NDFF + col;
    float a0 = 0.f, a1 = 0.f, a2 = 0.f, a3 = 0.f;
    #pragma unroll 4
    for (int dd = 0; dd < 128; ++dd) {
        float w = wp[(size_t)dd * NDFF];
        a0 += xs[dd] * w; a1 += xs[128 + dd] * w;
        a2 += xs[256 + dd] * w; a3 += xs[384 + dd] * w;
    }
    atomicAdd(&ws[dst + 0 * NDFF + col], a0);
    atomicAdd(&ws[dst + 1 * NDFF + col], a1);
    atomicAdd(&ws[dst + 2 * NDFF + col], a2);
    atomicAdd(&ws[dst + 3 * NDFF + col], a3);
}

// silu(gate)*up @ Wd -> y_mlp. grid (4 tiles, 16 f-splits)
__global__ __launch_bounds__(256) void k_down(const float* __restrict__ wd,
                                              float* __restrict__ ws, int l) {
    __shared__ float ts[1024];
    int tid = threadIdx.x;
    int f0 = blockIdx.y * 256;
    #pragma unroll
    for (int b = 0; b < 4; ++b) {
        float g = ws[WS_GATE + b * NDFF + f0 + tid];
        float u = ws[WS_UP + b * NDFF + f0 + tid];
        ts[b * 256 + tid] = (g / (1.f + __expf(-g))) * u;
    }
    __syncthreads();
    int col = blockIdx.x * 256 + tid;
    const float* wp = wd + (size_t)l * NDFF * ND + (size_t)f0 * ND + col;
    float a0 = 0.f, a1 = 0.f, a2 = 0.f, a3 = 0.f;
    #pragma unroll 4
    for (int ff = 0; ff < 256; ++ff) {
        float w = wp[(size_t)ff * ND];
        a0 += ts[ff] * w; a1 += ts[256 + ff] * w;
        a2 += ts[512 + ff] * w; a3 += ts[768 + ff] * w;
    }
    atomicAdd(&ws[WS_YMLP + 0 * 1024 + col], a0);
    atomicAdd(&ws[WS_YMLP + 1 * 1024 + col], a1);
    atomicAdd(&ws[WS_YMLP + 2 * 1024 + col], a2);
    atomicAdd(&ws[WS_YMLP + 3 * 1024 + col], a3);
}

__global__ __launch_bounds__(256) void k_final(const float* __restrict__ normw,
                                               float* __restrict__ ws,
                                               float* __restrict__ out) {
    int b = blockIdx.x, tid = threadIdx.x;
    int wave = tid >> 6, lane = tid & 63;
    __shared__ float sred[4];
    float hv[4]; float ss = 0.f;
    #pragma unroll
    for (int k = 0; k < 4; ++k) {
        int d = tid + k * 256;
        float nh = ws[WS_H + b * 1024 + d] + MUP * ws[WS_YMLP + b * 1024 + d];
        hv[k] = nh;
        ss += nh * nh;
    }
    ss = wsum(ss);
    if (lane == 0) sred[wave] = ss;
    __syncthreads();
    float tot = sred[0] + sred[1] + sred[2] + sred[3];
    float rstd = rsqrtf(tot / (float)ND + EPS);
    #pragma unroll
    for (int k = 0; k < 4; ++k) {
        int d = tid + k * 256;
        out[OUT_H + b * 1024 + d] = hv[k] * rstd * normw[d];
    }
}

extern "C" void kernel_launch(void* const* d_in, const int* in_sizes, int n_in,
                              void* d_out, int out_size, void* d_ws, size_t ws_size,
                              hipStream_t stream) {
    const float* emb  = (const float*)d_in[0];
    const float* kc   = (const float*)d_in[1];
    const float* vc   = (const float*)d_in[2];
    const float* ln1  = (const float*)d_in[3];
    const float* ln2  = (const float*)d_in[4];
    const float* nrmw = (const float*)d_in[5];
    const float* wq   = (const float*)d_in[6];
    const float* wk   = (const float*)d_in[7];
    const float* wv   = (const float*)d_in[8];
    const float* wo   = (const float*)d_in[9];
    const float* wg   = (const float*)d_in[10];
    const float* wu   = (const float*)d_in[11];
    const float* wd   = (const float*)d_in[12];
    const int*   cl   = (const int*)d_in[13];

    float* out = (float*)d_out;
    float* ws  = (float*)d_ws;
    float* nk  = out + OUT_NK;
    float* nv  = out + OUT_NV;

    k_init<<<8, 256, 0, stream>>>(emb, cl, ws, out);
    for (int l = 0; l < NL; ++l) {
        k_rms1<<<48, 256, 0, stream>>>(ln1, ws, l);
        k_qkv<<<dim3(8, 8), 256, 0, stream>>>(wq, wk, wv, ws, l);
        k_attn<<<NB * NKVH * NCHUNK, 256, 0, stream>>>(kc, vc, cl, ws, nk, nv, l);
        k_reduce<<<NB * NKVH, 64, 0, stream>>>(ws);
        k_oproj<<<dim3(4, 8), 256, 0, stream>>>(wo, ws, l);
        k_rms2<<<4, 256, 0, stream>>>(ln2, ws, l);
        k_gateup<<<dim3(16, 8, 2), 256, 0, stream>>>(wg, wu, ws, l);
        k_down<<<dim3(4, 16), 256, 0, stream>>>(wd, ws, l);
    }
    k_final<<<4, 256, 0, stream>>>(nrmw, ws, out);
}

// Round 2
// 1039.992 us; speedup vs baseline: 2.2823x; 2.2823x over previous
//
#include <hip/hip_runtime.h>
#include <math.h>

#define NL 16
#define NB 4
#define ND 1024
#define NH 16
#define HD 64
#define NKVH 8
#define NDFF 4096
#define NS 2048
#define SP1 2049
#define NCHUNK 16
#define MUP 0.35f       // 1.4/sqrt(16)
#define SCALE 0.125f    // 1/sqrt(64)
#define EPS 1e-5f

// workspace float offsets
#define WS_H     0
#define WS_X     4096
#define WS_QKV   8192      // [B][2048]: q 0..1023, k 1024..1535, v 1536..2047
#define WS_YO    16384     // [B][1024]
#define WS_GATE  20480     // [B][4096]
#define WS_UP    36864     // [B][4096]
#define WS_YMLP  53248     // [B][1024]
#define WS_OPART 57344     // [B][KVH][NCHUNK][132]

// d_out float offsets
#define OUT_H   0
#define OUT_NK  4096
#define OUT_NV  (4096 + NL*NB*NKVH*SP1*HD)
#define OUT_SC  (4096 + 2*NL*NB*NKVH*SP1*HD)

__device__ __forceinline__ float wsum64(float v) {
    v += __shfl_xor(v, 32); v += __shfl_xor(v, 16); v += __shfl_xor(v, 8);
    v += __shfl_xor(v, 4);  v += __shfl_xor(v, 2);  v += __shfl_xor(v, 1);
    return v;
}

__device__ __forceinline__ void fma4(float4& a, float s, const float4& w) {
    a.x = fmaf(s, w.x, a.x); a.y = fmaf(s, w.y, a.y);
    a.z = fmaf(s, w.z, a.z); a.w = fmaf(s, w.w, a.w);
}

__global__ __launch_bounds__(256) void k_init(const float* __restrict__ emb,
                                              const int* __restrict__ cl,
                                              float* __restrict__ ws,
                                              float* __restrict__ out) {
    float4* ws4 = (float4*)ws;
    int tid = threadIdx.x;
    if (blockIdx.x == 0) {
        const float4* e4 = (const float4*)emb;
        #pragma unroll
        for (int k = 0; k < 4; ++k) ws4[(WS_H >> 2) + k * 256 + tid] = e4[k * 256 + tid];
        if (tid == 0) out[OUT_SC] = (float)(cl[0] + 1);
    } else {
        float4 z = {0.f, 0.f, 0.f, 0.f};
        #pragma unroll
        for (int k = 0; k < 4; ++k) ws4[(WS_YMLP >> 2) + k * 256 + tid] = z;
    }
}

// blocks 0..3: h += mup*y_mlp; zero y_mlp; x = rmsnorm(h)*ln1
// blocks 4..14: zero qkv/yo/gate/up (45056 floats from WS_QKV)
__global__ __launch_bounds__(256) void k_rms1(const float* __restrict__ ln1,
                                              float* __restrict__ ws, int l) {
    float4* ws4 = (float4*)ws;
    int tid = threadIdx.x;
    if (blockIdx.x >= 4) {
        float4 z = {0.f, 0.f, 0.f, 0.f};
        int base4 = (WS_QKV >> 2) + (blockIdx.x - 4) * 1024;
        #pragma unroll
        for (int k = 0; k < 4; ++k) ws4[base4 + k * 256 + tid] = z;
        return;
    }
    int b = blockIdx.x, w = tid >> 6, lane = tid & 63;
    __shared__ float sred[4];
    float4 h4 = ws4[b * 256 + tid];
    float4 y4 = ws4[(WS_YMLP >> 2) + b * 256 + tid];
    h4.x += MUP * y4.x; h4.y += MUP * y4.y; h4.z += MUP * y4.z; h4.w += MUP * y4.w;
    float ss = h4.x * h4.x + h4.y * h4.y + h4.z * h4.z + h4.w * h4.w;
    ss = wsum64(ss);
    if (lane == 0) sred[w] = ss;
    ws4[b * 256 + tid] = h4;
    float4 z = {0.f, 0.f, 0.f, 0.f};
    ws4[(WS_YMLP >> 2) + b * 256 + tid] = z;
    __syncthreads();
    float rstd = rsqrtf((sred[0] + sred[1] + sred[2] + sred[3]) / (float)ND + EPS);
    float4 g4 = ((const float4*)ln1)[l * 256 + tid];
    float4 x4;
    x4.x = h4.x * rstd * g4.x; x4.y = h4.y * rstd * g4.y;
    x4.z = h4.z * rstd * g4.z; x4.w = h4.w * rstd * g4.w;
    ws4[(WS_X >> 2) + b * 256 + tid] = x4;
}

// x[4,1024] @ {Wq|Wk|Wv}. grid (8 col-tiles, 16 ksplit), block 256
__global__ __launch_bounds__(256) void k_qkv(const float* __restrict__ wq,
                                             const float* __restrict__ wk,
                                             const float* __restrict__ wv,
                                             float* __restrict__ ws, int l) {
    __shared__ float xs[256];          // [b][64]
    __shared__ float4 red[4][64][4];
    int tid = threadIdx.x, w = tid >> 6, lane = tid & 63;
    int x = blockIdx.x, y = blockIdx.y;
    xs[tid] = ws[WS_X + (tid >> 6) * 1024 + y * 64 + (tid & 63)];
    __syncthreads();
    const float* W; int nc, c;
    if (x < 4)      { W = wq + (size_t)l * 1024 * 1024; nc = 1024; c = x * 256 + lane * 4; }
    else if (x < 6) { W = wk + (size_t)l * 1024 * 512;  nc = 512;  c = (x - 4) * 256 + lane * 4; }
    else            { W = wv + (size_t)l * 1024 * 512;  nc = 512;  c = (x - 6) * 256 + lane * 4; }
    const float4* W4 = (const float4*)(W + c);
    size_t nc4 = nc >> 2;
    float4 a0 = {0,0,0,0}, a1 = a0, a2 = a0, a3 = a0;
    #pragma unroll 8
    for (int rr = 0; rr < 16; ++rr) {
        int r = w * 16 + rr;
        float4 wv4 = W4[(size_t)(y * 64 + r) * nc4];
        fma4(a0, xs[r], wv4); fma4(a1, xs[64 + r], wv4);
        fma4(a2, xs[128 + r], wv4); fma4(a3, xs[192 + r], wv4);
    }
    red[w][lane][0] = a0; red[w][lane][1] = a1; red[w][lane][2] = a2; red[w][lane][3] = a3;
    __syncthreads();
    if (w == 0) {
        int pcol = x * 256 + lane * 4;
        #pragma unroll
        for (int b = 0; b < 4; ++b) {
            float4 s = red[0][lane][b], t1 = red[1][lane][b], t2 = red[2][lane][b], t3 = red[3][lane][b];
            s.x += t1.x + t2.x + t3.x; s.y += t1.y + t2.y + t3.y;
            s.z += t1.z + t2.z + t3.z; s.w += t1.w + t2.w + t3.w;
            atomicAdd(&ws[WS_QKV + b * 2048 + pcol + 0], s.x);
            atomicAdd(&ws[WS_QKV + b * 2048 + pcol + 1], s.y);
            atomicAdd(&ws[WS_QKV + b * 2048 + pcol + 2], s.z);
            atomicAdd(&ws[WS_QKV + b * 2048 + pcol + 3], s.w);
        }
    }
}

// flash-decode partial + fused cache copy, float4. grid B*KVH*NCHUNK, block 256
__global__ __launch_bounds__(256) void k_attn(const float* __restrict__ kc,
                                              const float* __restrict__ vc,
                                              const int* __restrict__ cl,
                                              float* __restrict__ ws,
                                              float* __restrict__ nk,
                                              float* __restrict__ nv, int l) {
    int bid = blockIdx.x;
    int b   = bid / (NKVH * NCHUNK);
    int rem = bid % (NKVH * NCHUNK);
    int kvh = rem / NCHUNK;
    int c   = rem % NCHUNK;
    int s0 = c * 128;
    int tid = threadIdx.x, w = tid >> 6, lane = tid & 63;
    int sub = lane >> 4, j = lane & 15;

    float pos = (float)cl[0];
    float cs4[4], sn4[4];
    #pragma unroll
    for (int m = 0; m < 4; ++m) {
        float t = (float)(4 * (j & 7) + m);
        float fr = pos * __expf(-t * 0.2878231366242557f);  // ln(1e4)/32
        cs4[m] = cosf(fr); sn4[m] = sinf(fr);
    }
    float sgn = (j < 8) ? -1.f : 1.f;

    const float4* qp = (const float4*)(ws + WS_QKV + b * 2048 + kvh * 2 * 64);
    float4 q0 = qp[j], q1 = qp[16 + j];
    float4 q0p, q1p;
    q0p.x = __shfl_xor(q0.x, 8); q0p.y = __shfl_xor(q0.y, 8);
    q0p.z = __shfl_xor(q0.z, 8); q0p.w = __shfl_xor(q0.w, 8);
    q1p.x = __shfl_xor(q1.x, 8); q1p.y = __shfl_xor(q1.y, 8);
    q1p.z = __shfl_xor(q1.z, 8); q1p.w = __shfl_xor(q1.w, 8);
    q0.x = q0.x * cs4[0] + sgn * q0p.x * sn4[0];
    q0.y = q0.y * cs4[1] + sgn * q0p.y * sn4[1];
    q0.z = q0.z * cs4[2] + sgn * q0p.z * sn4[2];
    q0.w = q0.w * cs4[3] + sgn * q0p.w * sn4[3];
    q1.x = q1.x * cs4[0] + sgn * q1p.x * sn4[0];
    q1.y = q1.y * cs4[1] + sgn * q1p.y * sn4[1];
    q1.z = q1.z * cs4[2] + sgn * q1p.z * sn4[2];
    q1.w = q1.w * cs4[3] + sgn * q1p.w * sn4[3];

    __shared__ float sc[2][132];
    __shared__ float wm[2][4];
    __shared__ float oacc[2][4][64];
    __shared__ float wl[2][4];

    size_t cbase = (size_t)((l * NB + b) * NKVH + kvh);
    const float4* kc4 = (const float4*)(kc + cbase * (size_t)NS * 64);
    float4* nk4 = (float4*)(nk + cbase * (size_t)SP1 * 64);
    float m0 = -1e30f, m1 = -1e30f;
    int rbase = s0 + w * 32;
    #pragma unroll 4
    for (int i = 0; i < 8; ++i) {
        int r = rbase + i * 4 + sub;
        float4 kv = kc4[(size_t)r * 16 + j];
        nk4[(size_t)r * 16 + j] = kv;
        float d0 = kv.x * q0.x + kv.y * q0.y + kv.z * q0.z + kv.w * q0.w;
        float d1 = kv.x * q1.x + kv.y * q1.y + kv.z * q1.z + kv.w * q1.w;
        d0 += __shfl_xor(d0, 1); d0 += __shfl_xor(d0, 2);
        d0 += __shfl_xor(d0, 4); d0 += __shfl_xor(d0, 8);
        d1 += __shfl_xor(d1, 1); d1 += __shfl_xor(d1, 2);
        d1 += __shfl_xor(d1, 4); d1 += __shfl_xor(d1, 8);
        d0 *= SCALE; d1 *= SCALE;
        if (j == 0) { sc[0][r - s0] = d0; sc[1][r - s0] = d1; }
        m0 = fmaxf(m0, d0); m1 = fmaxf(m1, d1);
    }
    if (c == NCHUNK - 1 && w == 0 && sub == 0) {
        const float4* kn = (const float4*)(ws + WS_QKV + b * 2048 + 1024 + kvh * 64);
        float4 kv = kn[j];
        float4 kp;
        kp.x = __shfl_xor(kv.x, 8); kp.y = __shfl_xor(kv.y, 8);
        kp.z = __shfl_xor(kv.z, 8); kp.w = __shfl_xor(kv.w, 8);
        kv.x = kv.x * cs4[0] + sgn * kp.x * sn4[0];
        kv.y = kv.y * cs4[1] + sgn * kp.y * sn4[1];
        kv.z = kv.z * cs4[2] + sgn * kp.z * sn4[2];
        kv.w = kv.w * cs4[3] + sgn * kp.w * sn4[3];
        nk4[(size_t)NS * 16 + j] = kv;
        float d0 = kv.x * q0.x + kv.y * q0.y + kv.z * q0.z + kv.w * q0.w;
        float d1 = kv.x * q1.x + kv.y * q1.y + kv.z * q1.z + kv.w * q1.w;
        d0 += __shfl_xor(d0, 1); d0 += __shfl_xor(d0, 2);
        d0 += __shfl_xor(d0, 4); d0 += __shfl_xor(d0, 8);
        d1 += __shfl_xor(d1, 1); d1 += __shfl_xor(d1, 2);
        d1 += __shfl_xor(d1, 4); d1 += __shfl_xor(d1, 8);
        d0 *= SCALE; d1 *= SCALE;
        if (j == 0) { sc[0][128] = d0; sc[1][128] = d1; }
        m0 = fmaxf(m0, d0); m1 = fmaxf(m1, d1);
    }
    m0 = fmaxf(m0, __shfl_xor(m0, 16)); m0 = fmaxf(m0, __shfl_xor(m0, 32));
    m1 = fmaxf(m1, __shfl_xor(m1, 16)); m1 = fmaxf(m1, __shfl_xor(m1, 32));
    if (lane == 0) { wm[0][w] = m0; wm[1][w] = m1; }
    __syncthreads();
    float M0 = fmaxf(fmaxf(wm[0][0], wm[0][1]), fmaxf(wm[0][2], wm[0][3]));
    float M1 = fmaxf(fmaxf(wm[1][0], wm[1][1]), fmaxf(wm[1][2], wm[1][3]));

    const float4* vc4 = (const float4*)(vc + cbase * (size_t)NS * 64);
    float4* nv4 = (float4*)(nv + cbase * (size_t)SP1 * 64);
    float4 o0 = {0,0,0,0}, o1 = {0,0,0,0};
    float l0 = 0.f, l1 = 0.f;
    #pragma unroll 4
    for (int i = 0; i < 8; ++i) {
        int r = rbase + i * 4 + sub;
        float4 vv = vc4[(size_t)r * 16 + j];
        nv4[(size_t)r * 16 + j] = vv;
        float p0 = __expf(sc[0][r - s0] - M0);
        float p1 = __expf(sc[1][r - s0] - M1);
        fma4(o0, p0, vv); fma4(o1, p1, vv);
        l0 += p0; l1 += p1;
    }
    if (c == NCHUNK - 1 && w == 0 && sub == 0) {
        const float4* vn = (const float4*)(ws + WS_QKV + b * 2048 + 1536 + kvh * 64);
        float4 vv = vn[j];
        nv4[(size_t)NS * 16 + j] = vv;
        float p0 = __expf(sc[0][128] - M0);
        float p1 = __expf(sc[1][128] - M1);
        fma4(o0, p0, vv); fma4(o1, p1, vv);
        l0 += p0; l1 += p1;
    }
    o0.x += __shfl_xor(o0.x, 16); o0.x += __shfl_xor(o0.x, 32);
    o0.y += __shfl_xor(o0.y, 16); o0.y += __shfl_xor(o0.y, 32);
    o0.z += __shfl_xor(o0.z, 16); o0.z += __shfl_xor(o0.z, 32);
    o0.w += __shfl_xor(o0.w, 16); o0.w += __shfl_xor(o0.w, 32);
    o1.x += __shfl_xor(o1.x, 16); o1.x += __shfl_xor(o1.x, 32);
    o1.y += __shfl_xor(o1.y, 16); o1.y += __shfl_xor(o1.y, 32);
    o1.z += __shfl_xor(o1.z, 16); o1.z += __shfl_xor(o1.z, 32);
    o1.w += __shfl_xor(o1.w, 16); o1.w += __shfl_xor(o1.w, 32);
    l0 += __shfl_xor(l0, 16); l0 += __shfl_xor(l0, 32);
    l1 += __shfl_xor(l1, 16); l1 += __shfl_xor(l1, 32);
    if (sub == 0) {
        oacc[0][w][4 * j + 0] = o0.x; oacc[0][w][4 * j + 1] = o0.y;
        oacc[0][w][4 * j + 2] = o0.z; oacc[0][w][4 * j + 3] = o0.w;
        oacc[1][w][4 * j + 0] = o1.x; oacc[1][w][4 * j + 1] = o1.y;
        oacc[1][w][4 * j + 2] = o1.z; oacc[1][w][4 * j + 3] = o1.w;
    }
    if (lane == 0) { wl[0][w] = l0; wl[1][w] = l1; }
    __syncthreads();
    int pbase = WS_OPART + ((b * NKVH + kvh) * NCHUNK + c) * 132;
    if (tid < 128) {
        int h = tid >> 6, d = tid & 63;
        ws[pbase + h * 64 + d] = oacc[h][0][d] + oacc[h][1][d] + oacc[h][2][d] + oacc[h][3][d];
    } else if (tid == 128) {
        ws[pbase + 128] = M0;
        ws[pbase + 129] = wl[0][0] + wl[0][1] + wl[0][2] + wl[0][3];
        ws[pbase + 130] = M1;
        ws[pbase + 131] = wl[1][0] + wl[1][1] + wl[1][2] + wl[1][3];
    }
}

// chunk-reduce fused + o_heads @ Wo. grid (4 col-tiles, 16 ksplit), block 256
__global__ __launch_bounds__(256) void k_oproj(const float* __restrict__ wo,
                                               float* __restrict__ ws, int l) {
    __shared__ float xs[256];          // [b][64]
    __shared__ float4 red[4][64][4];
    int tid = threadIdx.x, w = tid >> 6, lane = tid & 63;
    int x = blockIdx.x, y = blockIdx.y;
    {
        int b = tid >> 6, rr = tid & 63;
        int r = y * 64 + rr;
        int kvh = r >> 7, g = (r >> 6) & 1, d = r & 63;
        int baseML = WS_OPART + ((b * NKVH + kvh) * NCHUNK) * 132;
        float m = -1e30f;
        #pragma unroll
        for (int cc = 0; cc < NCHUNK; ++cc)
            m = fmaxf(m, ws[baseML + cc * 132 + 128 + 2 * g]);
        float lt = 0.f, ot = 0.f;
        #pragma unroll
        for (int cc = 0; cc < NCHUNK; ++cc) {
            float f = __expf(ws[baseML + cc * 132 + 128 + 2 * g] - m);
            lt += ws[baseML + cc * 132 + 129 + 2 * g] * f;
            ot += ws[baseML + cc * 132 + g * 64 + d] * f;
        }
        xs[tid] = ot / lt;
    }
    __syncthreads();
    int c = x * 256 + lane * 4;
    const float4* W4 = (const float4*)(wo + (size_t)l * 1024 * 1024 + c);
    float4 a0 = {0,0,0,0}, a1 = a0, a2 = a0, a3 = a0;
    #pragma unroll 8
    for (int rr = 0; rr < 16; ++rr) {
        int r = w * 16 + rr;
        float4 wv4 = W4[(size_t)(y * 64 + r) * 256];
        fma4(a0, xs[r], wv4); fma4(a1, xs[64 + r], wv4);
        fma4(a2, xs[128 + r], wv4); fma4(a3, xs[192 + r], wv4);
    }
    red[w][lane][0] = a0; red[w][lane][1] = a1; red[w][lane][2] = a2; red[w][lane][3] = a3;
    __syncthreads();
    if (w == 0) {
        #pragma unroll
        for (int b = 0; b < 4; ++b) {
            float4 s = red[0][lane][b], t1 = red[1][lane][b], t2 = red[2][lane][b], t3 = red[3][lane][b];
            s.x += t1.x + t2.x + t3.x; s.y += t1.y + t2.y + t3.y;
            s.z += t1.z + t2.z + t3.z; s.w += t1.w + t2.w + t3.w;
            atomicAdd(&ws[WS_YO + b * 1024 + c + 0], s.x);
            atomicAdd(&ws[WS_YO + b * 1024 + c + 1], s.y);
            atomicAdd(&ws[WS_YO + b * 1024 + c + 2], s.z);
            atomicAdd(&ws[WS_YO + b * 1024 + c + 3], s.w);
        }
    }
}

__global__ __launch_bounds__(256) void k_rms2(const float* __restrict__ ln2,
                                              float* __restrict__ ws, int l) {
    float4* ws4 = (float4*)ws;
    int tid = threadIdx.x;
    int b = blockIdx.x, w = tid >> 6, lane = tid & 63;
    __shared__ float sred[4];
    float4 h4 = ws4[b * 256 + tid];
    float4 y4 = ws4[(WS_YO >> 2) + b * 256 + tid];
    h4.x += MUP * y4.x; h4.y += MUP * y4.y; h4.z += MUP * y4.z; h4.w += MUP * y4.w;
    float ss = h4.x * h4.x + h4.y * h4.y + h4.z * h4.z + h4.w * h4.w;
    ss = wsum64(ss);
    if (lane == 0) sred[w] = ss;
    ws4[b * 256 + tid] = h4;
    __syncthreads();
    float rstd = rsqrtf((sred[0] + sred[1] + sred[2] + sred[3]) / (float)ND + EPS);
    float4 g4 = ((const float4*)ln2)[l * 256 + tid];
    float4 x4;
    x4.x = h4.x * rstd * g4.x; x4.y = h4.y * rstd * g4.y;
    x4.z = h4.z * rstd * g4.z; x4.w = h4.w * rstd * g4.w;
    ws4[(WS_X >> 2) + b * 256 + tid] = x4;
}

// x @ {Wg|Wu}. grid (32 tiles [mat = x>>4], 8 ksplit), block 256
__global__ __launch_bounds__(256) void k_gateup(const float* __restrict__ wg,
                                                const float* __restrict__ wu,
                                                float* __restrict__ ws, int l) {
    __shared__ float xs[512];          // [b][128]
    __shared__ float4 red[4][64][4];
    int tid = threadIdx.x, w = tid >> 6, lane = tid & 63;
    int x = blockIdx.x, y = blockIdx.y;
    for (int t = tid; t < 512; t += 256)
        xs[t] = ws[WS_X + (t >> 7) * 1024 + y * 128 + (t & 127)];
    __syncthreads();
    int mat = x >> 4;
    int c = (x & 15) * 256 + lane * 4;
    const float* W = (mat ? wu : wg) + (size_t)l * 1024 * 4096;
    const float4* W4 = (const float4*)(W + c);
    float4 a0 = {0,0,0,0}, a1 = a0, a2 = a0, a3 = a0;
    #pragma unroll 8
    for (int rr = 0; rr < 32; ++rr) {
        int r = w * 32 + rr;
        float4 wv4 = W4[(size_t)(y * 128 + r) * 1024];
        fma4(a0, xs[r], wv4); fma4(a1, xs[128 + r], wv4);
        fma4(a2, xs[256 + r], wv4); fma4(a3, xs[384 + r], wv4);
    }
    red[w][lane][0] = a0; red[w][lane][1] = a1; red[w][lane][2] = a2; red[w][lane][3] = a3;
    __syncthreads();
    if (w == 0) {
        int dst = (mat ? WS_UP : WS_GATE) + c;
        #pragma unroll
        for (int b = 0; b < 4; ++b) {
            float4 s = red[0][lane][b], t1 = red[1][lane][b], t2 = red[2][lane][b], t3 = red[3][lane][b];
            s.x += t1.x + t2.x + t3.x; s.y += t1.y + t2.y + t3.y;
            s.z += t1.z + t2.z + t3.z; s.w += t1.w + t2.w + t3.w;
            atomicAdd(&ws[dst + b * 4096 + 0], s.x);
            atomicAdd(&ws[dst + b * 4096 + 1], s.y);
            atomicAdd(&ws[dst + b * 4096 + 2], s.z);
            atomicAdd(&ws[dst + b * 4096 + 3], s.w);
        }
    }
}

// silu(gate)*up @ Wd. grid (4 col-tiles, 32 fsplit), block 256
__global__ __launch_bounds__(256) void k_down(const float* __restrict__ wd,
                                              float* __restrict__ ws, int l) {
    __shared__ float ts[512];          // [b][128]
    __shared__ float4 red[4][64][4];
    int tid = threadIdx.x, w = tid >> 6, lane = tid & 63;
    int x = blockIdx.x, y = blockIdx.y;
    for (int t = tid; t < 512; t += 256) {
        int b = t >> 7, f = t & 127;
        float g = ws[WS_GATE + b * 4096 + y * 128 + f];
        float u = ws[WS_UP + b * 4096 + y * 128 + f];
        ts[t] = (g / (1.f + __expf(-g))) * u;
    }
    __syncthreads();
    int c = x * 256 + lane * 4;
    const float4* W4 = (const float4*)(wd + (size_t)l * 4096 * 1024 + c);
    float4 a0 = {0,0,0,0}, a1 = a0, a2 = a0, a3 = a0;
    #pragma unroll 8
    for (int rr = 0; rr < 32; ++rr) {
        int r = w * 32 + rr;
        float4 wv4 = W4[(size_t)(y * 128 + r) * 256];
        fma4(a0, ts[r], wv4); fma4(a1, ts[128 + r], wv4);
        fma4(a2, ts[256 + r], wv4); fma4(a3, ts[384 + r], wv4);
    }
    red[w][lane][0] = a0; red[w][lane][1] = a1; red[w][lane][2] = a2; red[w][lane][3] = a3;
    __syncthreads();
    if (w == 0) {
        #pragma unroll
        for (int b = 0; b < 4; ++b) {
            float4 s = red[0][lane][b], t1 = red[1][lane][b], t2 = red[2][lane][b], t3 = red[3][lane][b];
            s.x += t1.x + t2.x + t3.x; s.y += t1.y + t2.y + t3.y;
            s.z += t1.z + t2.z + t3.z; s.w += t1.w + t2.w + t3.w;
            atomicAdd(&ws[WS_YMLP + b * 1024 + c + 0], s.x);
            atomicAdd(&ws[WS_YMLP + b * 1024 + c + 1], s.y);
            atomicAdd(&ws[WS_YMLP + b * 1024 + c + 2], s.z);
            atomicAdd(&ws[WS_YMLP + b * 1024 + c + 3], s.w);
        }
    }
}

__global__ __launch_bounds__(256) void k_final(const float* __restrict__ normw,
                                               float* __restrict__ ws,
                                               float* __restrict__ out) {
    float4* ws4 = (float4*)ws;
    int tid = threadIdx.x;
    int b = blockIdx.x, w = tid >> 6, lane = tid & 63;
    __shared__ float sred[4];
    float4 h4 = ws4[b * 256 + tid];
    float4 y4 = ws4[(WS_YMLP >> 2) + b * 256 + tid];
    h4.x += MUP * y4.x; h4.y += MUP * y4.y; h4.z += MUP * y4.z; h4.w += MUP * y4.w;
    float ss = h4.x * h4.x + h4.y * h4.y + h4.z * h4.z + h4.w * h4.w;
    ss = wsum64(ss);
    if (lane == 0) sred[w] = ss;
    __syncthreads();
    float rstd = rsqrtf((sred[0] + sred[1] + sred[2] + sred[3]) / (float)ND + EPS);
    float4 g4 = ((const float4*)normw)[tid];
    float4 x4;
    x4.x = h4.x * rstd * g4.x; x4.y = h4.y * rstd * g4.y;
    x4.z = h4.z * rstd * g4.z; x4.w = h4.w * rstd * g4.w;
    ((float4*)out)[b * 256 + tid] = x4;
}

extern "C" void kernel_launch(void* const* d_in, const int* in_sizes, int n_in,
                              void* d_out, int out_size, void* d_ws, size_t ws_size,
                              hipStream_t stream) {
    const float* emb  = (const float*)d_in[0];
    const float* kc   = (const float*)d_in[1];
    const float* vc   = (const float*)d_in[2];
    const float* ln1  = (const float*)d_in[3];
    const float* ln2  = (const float*)d_in[4];
    const float* nrmw = (const float*)d_in[5];
    const float* wq   = (const float*)d_in[6];
    const float* wk   = (const float*)d_in[7];
    const float* wv   = (const float*)d_in[8];
    const float* wo   = (const float*)d_in[9];
    const float* wg   = (const float*)d_in[10];
    const float* wu   = (const float*)d_in[11];
    const float* wd   = (const float*)d_in[12];
    const int*   cl   = (const int*)d_in[13];

    float* out = (float*)d_out;
    float* ws  = (float*)d_ws;
    float* nk  = out + OUT_NK;
    float* nv  = out + OUT_NV;

    k_init<<<2, 256, 0, stream>>>(emb, cl, ws, out);
    for (int l = 0; l < NL; ++l) {
        k_rms1<<<15, 256, 0, stream>>>(ln1, ws, l);
        k_qkv<<<dim3(8, 16), 256, 0, stream>>>(wq, wk, wv, ws, l);
        k_attn<<<NB * NKVH * NCHUNK, 256, 0, stream>>>(kc, vc, cl, ws, nk, nv, l);
        k_oproj<<<dim3(4, 16), 256, 0, stream>>>(wo, ws, l);
        k_rms2<<<4, 256, 0, stream>>>(ln2, ws, l);
        k_gateup<<<dim3(32, 8), 256, 0, stream>>>(wg, wu, ws, l);
        k_down<<<dim3(4, 32), 256, 0, stream>>>(wd, ws, l);
    }
    k_final<<<4, 256, 0, stream>>>(nrmw, ws, out);
}